// Round 8
// baseline (92.422 us; speedup 1.0000x reference)
//
#include <hip/hip_runtime.h>
#include <math.h>

#define BHn 16
#define SLEN 4096
#define Dd 64
#define Cc 64
#define NCC 64
#define EPSF 1e-6f
#define PD 65

// ---------------------------------------------------------------------------
// kA round-8: readlane solve WITH round-0's acc[8] blocking (clean test of
// the solve-LDS-congestion model; round-6's version was confounded by flat
// sol[] indexing that tripled AGPR round-trips).
//   * S-phase stores the strict-lower triangle into per-lane segments:
//     element e = i(i-1)/2+j lives at SMf[36*(e>>5) + (e&31)] -- segment
//     stride 36 floats = 144 B (16B-aligned => the per-lane b128 loads are
//     legal, fixing r6's 33-float-stride alignment bug).
//   * Each solve lane preloads its 32-element segment (8 aligned b128), then
//     the elimination runs round-0's exact block order with SM values
//     broadcast via __builtin_amdgcn_readlane (VALU, per-SIMD) -- the 672
//     wave-uniform LDS reads per wave (8 waves/CU serialized on one LDS
//     unit, ~22 us modeled) disappear from the LDS pipe.
// Two parallel solve waves (wave0 = W, wave1 = U), 4 blocks/CU, as round-0.
// ---------------------------------------------------------------------------
__global__ __launch_bounds__(256, 4) void kA(
    const float* __restrict__ kg, const float* __restrict__ vg,
    const float* __restrict__ betag, float* __restrict__ WTg, float* __restrict__ UTg,
    float* __restrict__ wlast, float* __restrict__ ulast)
{
    const int n = blockIdx.x, bh = blockIdx.y, tid = threadIdx.x;
    __shared__ float KT[64 * PD];   // kn^T, then (g*v)^T
    __shared__ float SMf[64 * 36];  // strict-lower SM in per-lane segments
    __shared__ float gl[64];

    const size_t base = ((size_t)bh * SLEN + (size_t)n * Cc) * Dd;

    if (tid < 64) {
        const float b = betag[(size_t)bh * SLEN + n * Cc + tid];
        gl[tid] = fminf(fmaxf(b, EPSF), 1.0f - EPSF);
    }
    // build KT = kn^T : coalesced float4 row loads, 16-lane norm, transposed
    // scalar writes (bank = (d+t)%32, exactly 2 lanes/bank => free)
#pragma unroll
    for (int p = 0; p < 4; p++) {
        const int flat = p * 1024 + tid * 4;
        const int row = flat >> 6, d0 = flat & 63;
        const float4 a = *(const float4*)(kg + base + flat);
        float ss = a.x * a.x + a.y * a.y + a.z * a.z + a.w * a.w;
        ss += __shfl_xor(ss, 1); ss += __shfl_xor(ss, 2);
        ss += __shfl_xor(ss, 4); ss += __shfl_xor(ss, 8);
        const float inv = 1.0f / (sqrtf(ss) + EPSF);
        KT[(d0 + 0) * PD + row] = a.x * inv;
        KT[(d0 + 1) * PD + row] = a.y * inv;
        KT[(d0 + 2) * PD + row] = a.z * inv;
        KT[(d0 + 3) * PD + row] = a.w * inv;
    }
    __syncthreads();

    float sol[64];
    if (tid < 64) {
        // wave0: load W solve column = KT[tid][:] * g[:]  (concurrent with S)
#pragma unroll
        for (int j4 = 0; j4 < 16; j4++) {
            const float4 t4 = *(const float4*)&KT[tid * PD + j4 * 4];
            sol[j4 * 4 + 0] = t4.x * gl[j4 * 4 + 0];
            sol[j4 * 4 + 1] = t4.y * gl[j4 * 4 + 1];
            sol[j4 * 4 + 2] = t4.z * gl[j4 * 4 + 2];
            sol[j4 * 4 + 3] = t4.w * gl[j4 * 4 + 3];
        }
    } else if (tid < 200) {
        // threads 64..199: S lower 4x4 tiles from KT; rows scaled by g_i;
        // scalar stores into the segmented triangle (strict-lower only)
        const int t = tid - 64;
        int ti = (int)((sqrtf(8.0f * (float)t + 1.0f) - 1.0f) * 0.5f);
        while (ti * (ti + 1) / 2 > t) --ti;
        while ((ti + 1) * (ti + 2) / 2 <= t) ++ti;
        const int tj = t - ti * (ti + 1) / 2;
        const int i0 = ti * 4, j0 = tj * 4;
        float sa[4][4];
#pragma unroll
        for (int r = 0; r < 4; r++)
#pragma unroll
            for (int c2 = 0; c2 < 4; c2++) sa[r][c2] = 0.f;
        for (int d = 0; d < 64; d++) {
            const float4 a = *(const float4*)&KT[d * PD + i0];
            const float4 b = *(const float4*)&KT[d * PD + j0];
            const float av[4] = {a.x, a.y, a.z, a.w};
            const float bv[4] = {b.x, b.y, b.z, b.w};
#pragma unroll
            for (int r = 0; r < 4; r++)
#pragma unroll
                for (int c2 = 0; c2 < 4; c2++) sa[r][c2] += av[r] * bv[c2];
        }
#pragma unroll
        for (int r = 0; r < 4; r++) {
            const int i = i0 + r;
            const int eb = (i * (i - 1)) / 2 + j0;
            const float gg = gl[i];
#pragma unroll
            for (int c2 = 0; c2 < 4; c2++) {
                if (ti != tj || c2 < r) {
                    const int e = eb + c2;
                    SMf[36 * (e >> 5) + (e & 31)] = sa[r][c2] * gg;
                }
            }
        }
    }
    __syncthreads();

    // overwrite KT with (g*v)^T
#pragma unroll
    for (int p = 0; p < 4; p++) {
        const int flat = p * 1024 + tid * 4;
        const int row = flat >> 6, d0 = flat & 63;
        const float4 a = *(const float4*)(vg + base + flat);
        const float gg = gl[row];
        KT[(d0 + 0) * PD + row] = a.x * gg;
        KT[(d0 + 1) * PD + row] = a.y * gg;
        KT[(d0 + 2) * PD + row] = a.z * gg;
        KT[(d0 + 3) * PD + row] = a.w * gg;
    }
    __syncthreads();

    if (tid >= 64 && tid < 128) {
        // wave1: load U solve column = (g*v)^T row
        const int c = tid - 64;
#pragma unroll
        for (int j4 = 0; j4 < 16; j4++) {
            const float4 t4 = *(const float4*)&KT[c * PD + j4 * 4];
            sol[j4 * 4 + 0] = t4.x; sol[j4 * 4 + 1] = t4.y;
            sol[j4 * 4 + 2] = t4.z; sol[j4 * 4 + 3] = t4.w;
        }
    }
    if (tid < 128) {
        const int c = tid & 63;
        // preload this lane's 32-element SM segment (8 aligned b128 reads)
        float sm[32];
        {
            const int lb = 36 * c;
#pragma unroll
            for (int r8 = 0; r8 < 8; r8++) {
                const float4 t4 = *(const float4*)&SMf[lb + r8 * 4];
                sm[r8 * 4 + 0] = t4.x; sm[r8 * 4 + 1] = t4.y;
                sm[r8 * 4 + 2] = t4.z; sm[r8 * 4 + 3] = t4.w;
            }
        }
        // register forward substitution -- round-0 block order, SM values
        // broadcast via readlane (static lane/index, rule-#20 safe)
#pragma unroll
        for (int b = 0; b < 8; b++) {
            const int i0 = b * 8;
            float acc[8];
#pragma unroll
            for (int r = 0; r < 8; r++) acc[r] = sol[i0 + r];
#pragma unroll
            for (int j = 0; j < 8 * b; j++) {
                const float sj = sol[j];
#pragma unroll
                for (int r = 0; r < 8; r++) {
                    const int e = ((i0 + r) * (i0 + r - 1)) / 2 + j;
                    const float s = __int_as_float(__builtin_amdgcn_readlane(
                        __float_as_int(sm[e & 31]), e >> 5));
                    acc[r] -= s * sj;
                }
            }
#pragma unroll
            for (int il = 1; il < 8; il++)
#pragma unroll
                for (int jl = 0; jl < il; jl++) {
                    const int e = ((i0 + il) * (i0 + il - 1)) / 2 + i0 + jl;
                    const float s = __int_as_float(__builtin_amdgcn_readlane(
                        __float_as_int(sm[e & 31]), e >> 5));
                    acc[il] -= s * acc[jl];
                }
#pragma unroll
            for (int r = 0; r < 8; r++) sol[i0 + r] = acc[r];
        }
        // stores straight from registers: row c of W^T/U^T ([dim][token])
        float* dst = (tid < 64 ? WTg : UTg) +
                     (size_t)(bh * NCC + n) * Cc * Dd + (size_t)c * 64;
#pragma unroll
        for (int j4 = 0; j4 < 16; j4++)
            *(float4*)(dst + j4 * 4) = make_float4(sol[j4 * 4 + 0], sol[j4 * 4 + 1],
                                                   sol[j4 * 4 + 2], sol[j4 * 4 + 3]);
        float* lst = (tid < 64 ? wlast : ulast);
        lst[(size_t)(bh * NCC + n) * 64 + c] = sol[63];
    }
}

// ---------------------------------------------------------------------------
// kB: chunk-level delta rule (16 blocks). Register solve.  (unchanged)
// ---------------------------------------------------------------------------
__global__ __launch_bounds__(256) void kB(
    const float* __restrict__ wlast, const float* __restrict__ ulast,
    float* __restrict__ Uvg)
{
    const int bh = blockIdx.x, tid = threadIdx.x;
    __shared__ float WL[64 * PD];
    __shared__ float UL[64 * PD];
    __shared__ float SM[64 * PD];
    const size_t gbase = (size_t)bh * NCC * 64;

#pragma unroll
    for (int p = 0; p < 4; p++) {
        const int flat = p * 1024 + tid * 4;
        const int m = flat >> 6, d = flat & 63;
        *(float4*)&WL[m * PD + d] = *(const float4*)(wlast + gbase + flat);
        *(float4*)&UL[m * PD + d] = *(const float4*)(ulast + gbase + flat);
    }
    __syncthreads();

    if (tid < 136) {
        int ti = (int)((sqrtf(8.0f * (float)tid + 1.0f) - 1.0f) * 0.5f);
        while (ti * (ti + 1) / 2 > tid) --ti;
        while ((ti + 1) * (ti + 2) / 2 <= tid) ++ti;
        const int tj = tid - ti * (ti + 1) / 2;
        const int i0 = ti * 4, j0 = tj * 4;
        float sa[4][4];
#pragma unroll
        for (int r = 0; r < 4; r++)
#pragma unroll
            for (int c2 = 0; c2 < 4; c2++) sa[r][c2] = 0.f;
        for (int d4 = 0; d4 < 16; d4++) {
            const int d = d4 * 4;
            float4 ar[4], bc[4];
#pragma unroll
            for (int r = 0; r < 4; r++) ar[r] = *(const float4*)&WL[(i0 + r) * PD + d];
#pragma unroll
            for (int c2 = 0; c2 < 4; c2++) bc[c2] = *(const float4*)&WL[(j0 + c2) * PD + d];
#pragma unroll
            for (int r = 0; r < 4; r++)
#pragma unroll
                for (int c2 = 0; c2 < 4; c2++)
                    sa[r][c2] += ar[r].x * bc[c2].x + ar[r].y * bc[c2].y +
                                 ar[r].z * bc[c2].z + ar[r].w * bc[c2].w;
        }
#pragma unroll
        for (int r = 0; r < 4; r++)
            *(float4*)&SM[(i0 + r) * PD + j0] =
                make_float4(sa[r][0], sa[r][1], sa[r][2], sa[r][3]);
    }
    __syncthreads();

    if (tid < 64) {
        const int e = tid;
        float sol[64];
#pragma unroll
        for (int m = 0; m < 64; m++) sol[m] = UL[m * PD + e];
#pragma unroll
        for (int b = 0; b < 8; b++) {
            const int i0 = b * 8;
            float acc[8];
#pragma unroll
            for (int r = 0; r < 8; r++) acc[r] = sol[i0 + r];
#pragma unroll
            for (int j4 = 0; j4 < 2 * b; j4++) {
                const int j = j4 * 4;
                const float s0 = sol[j + 0], s1 = sol[j + 1];
                const float s2 = sol[j + 2], s3 = sol[j + 3];
#pragma unroll
                for (int r = 0; r < 8; r++) {
                    const float4 m4 = *(const float4*)&SM[(i0 + r) * PD + j];
                    acc[r] -= m4.x * s0 + m4.y * s1 + m4.z * s2 + m4.w * s3;
                }
            }
#pragma unroll
            for (int il = 1; il < 8; il++)
#pragma unroll
                for (int jl = 0; jl < il; jl++)
                    acc[il] -= SM[(i0 + il) * PD + i0 + jl] * acc[jl];
#pragma unroll
            for (int r = 0; r < 8; r++) sol[i0 + r] = acc[r];
        }
#pragma unroll
        for (int m = 0; m < 64; m++) Uvg[gbase + (size_t)m * 64 + e] = sol[m];
    }
}

// ---------------------------------------------------------------------------
// kC: single-chunk blocks (round-7 form, measured == round-0).  1024 blocks;
// heavy chunks first (n = 63-bx) so greedy scheduling absorbs ph1 imbalance.
//   h[d][e] = sum_{m<n} wlast[m][d]*Uval[m][e];  out = qn.*(U - W h) + qn h
// ---------------------------------------------------------------------------
__global__ __launch_bounds__(256, 3) void kC(
    const float* __restrict__ qg, const float* __restrict__ WTg,
    const float* __restrict__ UTg, const float* __restrict__ wlast,
    const float* __restrict__ Uvg, float* __restrict__ outg)
{
    const int bx = blockIdx.x, bh = blockIdx.y, tid = threadIdx.x;
    __shared__ float X1[64 * 64];   // wlast[m][d] -> W^T[d][t]
    __shared__ float X2[64 * PD];   // Uval[m][e]  -> qn^T[d][t]  (padded)
    __shared__ float HB[64 * 64];   // h[d][e]
    const size_t lbase = (size_t)bh * NCC * 64;
    const int t0 = (tid >> 4) * 4, e0 = (tid & 15) * 4;

    const int n = 63 - bx;   // heavy chunks dispatched first
    const size_t qbase = ((size_t)bh * SLEN + (size_t)n * Cc) * Dd;
    const size_t wbase = (size_t)(bh * NCC + n) * Cc * Dd;

    float4 qa[4], wt[4];
    float qinv[4];
#pragma unroll
    for (int p = 0; p < 4; p++) {
        const int flat = p * 1024 + tid * 4;
        const int m = flat >> 6, d = flat & 63;
        *(float4*)&X1[m * 64 + d] = *(const float4*)(wlast + lbase + flat);
        *(float4*)&X2[m * PD + d] = *(const float4*)(Uvg + lbase + flat);
        qa[p] = *(const float4*)(qg + qbase + flat);
        float ss = qa[p].x * qa[p].x + qa[p].y * qa[p].y +
                   qa[p].z * qa[p].z + qa[p].w * qa[p].w;
        ss += __shfl_xor(ss, 1); ss += __shfl_xor(ss, 2);
        ss += __shfl_xor(ss, 4); ss += __shfl_xor(ss, 8);
        qinv[p] = 1.0f / (sqrtf(ss) + EPSF);
        wt[p] = *(const float4*)(WTg + wbase + flat);
    }
    __syncthreads();

    // ph1: h tile accumulation over earlier chunks
    float ha[4][4];
#pragma unroll
    for (int r = 0; r < 4; r++)
#pragma unroll
        for (int c2 = 0; c2 < 4; c2++) ha[r][c2] = 0.f;
    for (int m = 0; m < n; m++) {
        const float4 a = *(const float4*)&X1[m * 64 + t0];
        const float4 b = *(const float4*)&X2[m * PD + e0];
        const float av[4] = {a.x, a.y, a.z, a.w};
        const float bv[4] = {b.x, b.y, b.z, b.w};
#pragma unroll
        for (int r = 0; r < 4; r++)
#pragma unroll
            for (int c2 = 0; c2 < 4; c2++) ha[r][c2] += av[r] * bv[c2];
    }
#pragma unroll
    for (int r = 0; r < 4; r++)
        *(float4*)&HB[(t0 + r) * 64 + e0] =
            make_float4(ha[r][0], ha[r][1], ha[r][2], ha[r][3]);
    __syncthreads();

    // rebuild: X1 <- W^T (flat from regs), X2 <- qn^T (transposed writes)
#pragma unroll
    for (int p = 0; p < 4; p++) {
        const int flat = p * 1024 + tid * 4;
        const int d = flat >> 6, t = flat & 63;
        *(float4*)&X1[d * 64 + t] = wt[p];
        const int row = d, d0 = t;   // q decode: (token row, dim d0)
        X2[(d0 + 0) * PD + row] = qa[p].x * qinv[p];
        X2[(d0 + 1) * PD + row] = qa[p].y * qinv[p];
        X2[(d0 + 2) * PD + row] = qa[p].z * qinv[p];
        X2[(d0 + 3) * PD + row] = qa[p].w * qinv[p];
    }
    __syncthreads();

    // ph3: kth = W h, oin = qn h
    float kth[4][4], oin[4][4];
#pragma unroll
    for (int r = 0; r < 4; r++)
#pragma unroll
        for (int c2 = 0; c2 < 4; c2++) { kth[r][c2] = 0.f; oin[r][c2] = 0.f; }
#pragma unroll 4
    for (int d = 0; d < 64; d++) {
        const float4 wv = *(const float4*)&X1[d * 64 + t0];
        const float4 qv = *(const float4*)&X2[d * PD + t0];
        const float4 hv = *(const float4*)&HB[d * 64 + e0];
        const float wa[4] = {wv.x, wv.y, wv.z, wv.w};
        const float qa2[4] = {qv.x, qv.y, qv.z, qv.w};
        const float hv4[4] = {hv.x, hv.y, hv.z, hv.w};
#pragma unroll
        for (int r = 0; r < 4; r++)
#pragma unroll
            for (int c2 = 0; c2 < 4; c2++) {
                kth[r][c2] += wa[r] * hv4[c2];
                oin[r][c2] += qa2[r] * hv4[c2];
            }
    }

    // epilogue: U^T tile from global (L2-hot), qn from X2
    float* oc = outg + qbase;
    float o4[4][4];
#pragma unroll
    for (int s = 0; s < 4; s++) {
        const float4 u4 = *(const float4*)(UTg + wbase + (size_t)(e0 + s) * 64 + t0);
        const float4 q4 = *(const float4*)&X2[(e0 + s) * PD + t0];
        o4[0][s] = q4.x * (u4.x - kth[0][s]) + oin[0][s];
        o4[1][s] = q4.y * (u4.y - kth[1][s]) + oin[1][s];
        o4[2][s] = q4.z * (u4.z - kth[2][s]) + oin[2][s];
        o4[3][s] = q4.w * (u4.w - kth[3][s]) + oin[3][s];
    }
#pragma unroll
    for (int r = 0; r < 4; r++)
        *(float4*)(oc + (size_t)(t0 + r) * 64 + e0) =
            make_float4(o4[r][0], o4[r][1], o4[r][2], o4[r][3]);
}

extern "C" void kernel_launch(void* const* d_in, const int* in_sizes, int n_in,
                              void* d_out, int out_size, void* d_ws, size_t ws_size,
                              hipStream_t stream) {
    const float* q    = (const float*)d_in[0];
    const float* k    = (const float*)d_in[1];
    const float* v    = (const float*)d_in[2];
    const float* beta = (const float*)d_in[3];
    float* out = (float*)d_out;

    float* WTg   = (float*)d_ws;                              // [BH][NC][64][64] (W^T)
    float* UTg   = WTg + (size_t)BHn * NCC * Cc * Dd;         // [BH][NC][64][64] (U^T)
    float* wlast = UTg + (size_t)BHn * NCC * Cc * Dd;         // [BH][NC][64]
    float* ulast = wlast + (size_t)BHn * NCC * 64;            // [BH][NC][64]
    float* Uvg   = ulast + (size_t)BHn * NCC * 64;            // [BH][NC][64]

    kA<<<dim3(NCC, BHn), 256, 0, stream>>>(k, v, beta, WTg, UTg, wlast, ulast);
    kB<<<dim3(BHn), 256, 0, stream>>>(wlast, ulast, Uvg);
    kC<<<dim3(64, BHn), 256, 0, stream>>>(q, WTg, UTg, wlast, Uvg, out);
}